// Round 6
// baseline (232.169 us; speedup 1.0000x reference)
//
#include <hip/hip_runtime.h>
#include <stdint.h>

#define N_NODES 100000
#define N_FEAT 128
#define N_EDGES 3200000

// ---------- bf16 helpers ----------
static __device__ __forceinline__ unsigned int f2bf_u(float f) {
    unsigned int u = __float_as_uint(f);
    u += 0x7FFFu + ((u >> 16) & 1u);   // RNE
    return u >> 16;
}

typedef __bf16 bf16x8 __attribute__((ext_vector_type(8)));
typedef float f32x4 __attribute__((ext_vector_type(4)));

// ---------- Kernel 1 (fused prep) ----------
// blocks [0,12500):      x fp32 -> int8 row-quantized (2 nodes/wave, float4 loads)
// blocks [12500,25000):  CSR row_ptr scatter from sorted edge_dst
// blocks [25000,25064):  filters -> F^T bf16
__global__ __launch_bounds__(256) void k_prep(
        const float* __restrict__ x, unsigned int* __restrict__ xi8,
        float* __restrict__ xscale,
        const float* __restrict__ f, unsigned short* __restrict__ fT,
        const int* __restrict__ dst, int* __restrict__ row_ptr) {
    int b = blockIdx.x;
    if (b < 12500) {
        int wave = threadIdx.x >> 6, lane = threadIdx.x & 63;
        int l32 = lane & 31;
        int node = b * 8 + wave * 2 + (lane >> 5);
        float4 v = *(const float4*)(x + (size_t)node * 128 + l32 * 4);
        float am = fmaxf(fmaxf(fabsf(v.x), fabsf(v.y)), fmaxf(fabsf(v.z), fabsf(v.w)));
        for (int d = 1; d < 32; d <<= 1) am = fmaxf(am, __shfl_xor(am, d));
        float s = am * (1.f / 127.f);
        float inv = 127.f / fmaxf(am, 1e-20f);
        int q0 = (int)rintf(v.x * inv), q1 = (int)rintf(v.y * inv);
        int q2 = (int)rintf(v.z * inv), q3 = (int)rintf(v.w * inv);
        xi8[(size_t)node * 32 + l32] = (unsigned int)((q0 & 0xFF) | ((q1 & 0xFF) << 8) |
                                                      ((q2 & 0xFF) << 16) | ((q3 & 0xFF) << 24));
        if (l32 == 0) xscale[node] = s;
    } else if (b < 25000) {
        int e = (b - 12500) * 256 + threadIdx.x;
        if (e >= N_EDGES) return;
        int dcur = dst[e];
        if (e == 0) {
            for (int d = 0; d <= dcur; ++d) row_ptr[d] = 0;
        } else {
            int dprev = dst[e - 1];
            for (int d = dprev + 1; d <= dcur; ++d) row_ptr[d] = e;
        }
        if (e == N_EDGES - 1) {
            for (int d = dcur + 1; d <= N_NODES; ++d) row_ptr[d] = N_EDGES;
        }
    } else {
        int i = (b - 25000) * 256 + threadIdx.x;   // i = k*128 + n
        if (i >= N_FEAT * N_FEAT) return;
        int k = i >> 7, n = i & 127;
        fT[n * N_FEAT + k] = (unsigned short)f2bf_u(f[i]);
    }
}

// ---------- Kernel 2: fused aggregate + GEMM ----------
// Block = 64 nodes, 512 threads (8 waves).
// Phase A: wave w aggregates nodes base+8w..+7 (int8 gather, fp32 acc),
//          writes bf16 rows into LDS Abuf. B^T staged to LDS at entry.
// Phase B: wave w computes C strip rows 0..63 x cols 16w..16w+15 via MFMA.
// Phase C: acc -> LDS Cbuf (overlaid) -> coalesced float4 global stores.
#define LDA 136   // shorts per LDS row (+8 pad)
#define LDC 132   // floats per Cbuf row

__global__ __launch_bounds__(512, 4) void k_agg_gemm(
        const unsigned int* __restrict__ xi8,    // [N][32] uints (4 int8)
        const float* __restrict__ xscale,        // [N]
        const int* __restrict__ src,
        const float* __restrict__ w,
        const int* __restrict__ row_ptr,
        const unsigned short* __restrict__ BT,   // [128][128] bf16 (F^T)
        float* __restrict__ C) {                 // [N][128] fp32
    __shared__ uint4 lds[3520];                  // 56320 B
    uint2*          smeta = (uint2*)lds;                              // 8*64*8   = 4096 B
    unsigned short* Abuf  = (unsigned short*)((char*)lds + 4096);     // 64*136*2 = 17408 B
    unsigned short* Bbuf  = (unsigned short*)((char*)lds + 4096 + 17408); // 128*136*2 = 34816 B
    float*          Cbuf  = (float*)lds;                              // 64*132*4 = 33792 B (overlay)

    int t = threadIdx.x;
    int wave = t >> 6, lane = t & 63;
    int base = blockIdx.x * 64;

    // stage B^T -> Bbuf (independent of phase A; barrier below covers it)
    for (int i = 0; i < 4; ++i) {
        int idx = t + i * 512;                   // 2048 uint4 chunks
        int r = idx >> 4, c8 = idx & 15;
        *(uint4*)(Bbuf + r * LDA + c8 * 8) = *(const uint4*)(BT + r * 128 + c8 * 8);
    }

    // ---- Phase A: aggregation (round-5 inner loop) ----
    int half = lane >> 5, ffeat = lane & 31;
    for (int n = 0; n < 8; ++n) {
        int node = base + wave * 8 + n;
        if (node >= N_NODES) break;              // wave-uniform
        int start = row_ptr[node], end = row_ptr[node + 1];
        float a0 = 0.f, a1 = 0.f, a2 = 0.f, a3 = 0.f;
        for (int e0 = start; e0 < end; e0 += 64) {
            int e = e0 + lane;
            uint2 m = make_uint2(0u, 0u);        // pad: src=0, w'=0
            if (e < end) {
                int sv = src[e];
                m.x = (unsigned int)sv;
                m.y = __float_as_uint(w[e] * xscale[sv]);
            }
            smeta[wave * 64 + lane] = m;         // wave-private; no barrier
            int cnt16 = (min(64, end - e0) + 15) & ~15;
            for (int j = 0; j < cnt16; j += 16) {
                unsigned int vv[8]; float wj[8];
#pragma unroll
                for (int u = 0; u < 8; ++u) {
                    uint2 mm = smeta[wave * 64 + j + u * 2 + half];
                    wj[u] = __uint_as_float(mm.y);
                    vv[u] = xi8[mm.x * 32 + ffeat];
                }
#pragma unroll
                for (int u = 0; u < 8; ++u) {
                    int s32 = (int)vv[u];
                    a0 = fmaf(wj[u], (float)((s32 << 24) >> 24), a0);
                    a1 = fmaf(wj[u], (float)((s32 << 16) >> 24), a1);
                    a2 = fmaf(wj[u], (float)((s32 <<  8) >> 24), a2);
                    a3 = fmaf(wj[u], (float)( s32        >> 24), a3);
                }
            }
        }
        a0 += __shfl_xor(a0, 32);
        a1 += __shfl_xor(a1, 32);
        a2 += __shfl_xor(a2, 32);
        a3 += __shfl_xor(a3, 32);
        if (half == 0) {
            uint2 o;
            o.x = (f2bf_u(a1) << 16) | f2bf_u(a0);
            o.y = (f2bf_u(a3) << 16) | f2bf_u(a2);
            *(uint2*)(Abuf + (wave * 8 + n) * LDA + ffeat * 4) = o;
        }
    }
    __syncthreads();

    // ---- Phase B: GEMM strip (cols 16*wave .. +15, rows 0..63) ----
    int m15 = lane & 15, q = lane >> 4;
    f32x4 acc[4];
    for (int i = 0; i < 4; ++i) acc[i] = f32x4{0.f, 0.f, 0.f, 0.f};
    for (int kk = 0; kk < 128; kk += 32) {
        bf16x8 bfr = *(const bf16x8*)(Bbuf + (wave * 16 + m15) * LDA + kk + q * 8);
#pragma unroll
        for (int i = 0; i < 4; ++i) {
            bf16x8 afr = *(const bf16x8*)(Abuf + (i * 16 + m15) * LDA + kk + q * 8);
            acc[i] = __builtin_amdgcn_mfma_f32_16x16x32_bf16(afr, bfr, acc[i], 0, 0, 0);
        }
    }
    __syncthreads();                             // Abuf/Bbuf dead; reuse as Cbuf

    // ---- Phase C: transpose via LDS, coalesced stores ----
    for (int i = 0; i < 4; ++i)
#pragma unroll
        for (int r = 0; r < 4; ++r)
            Cbuf[(i * 16 + q * 4 + r) * LDC + wave * 16 + m15] = acc[i][r];
    __syncthreads();
    for (int it = 0; it < 4; ++it) {
        int idx = t + it * 512;                  // 2048 float4 chunks
        int row = idx >> 5, c4 = (idx & 31) * 4;
        int grow = base + row;
        if (grow < N_NODES)
            *(float4*)(C + (size_t)grow * 128 + c4) = *(const float4*)(Cbuf + row * LDC + c4);
    }
}

extern "C" void kernel_launch(void* const* d_in, const int* in_sizes, int n_in,
                              void* d_out, int out_size, void* d_ws, size_t ws_size,
                              hipStream_t stream) {
    const float* x        = (const float*)d_in[0];
    const float* filters  = (const float*)d_in[1];
    const int*   edge_src = (const int*)d_in[2];
    const int*   edge_dst = (const int*)d_in[3];
    const float* edge_w   = (const float*)d_in[4];
    float* out = (float*)d_out;

    char* ws = (char*)d_ws;
    unsigned int*   xi8  = (unsigned int*)  (ws);                          // 12.8 MB
    float*          xsc  = (float*)         (ws + 13ll * 1024 * 1024);     // 400 KB
    unsigned short* fT   = (unsigned short*)(ws + 14ll * 1024 * 1024);     // 32 KB
    int*            rp   = (int*)           (ws + 15ll * 1024 * 1024);     // 400 KB

    hipLaunchKernelGGL(k_prep, dim3(25064), dim3(256), 0, stream,
                       x, xi8, xsc, filters, fT, edge_dst, rp);
    hipLaunchKernelGGL(k_agg_gemm, dim3(1563), dim3(512), 0, stream,
                       xi8, xsc, edge_src, edge_w, rp, fT, out);
}

// Round 7
// 200.881 us; speedup vs baseline: 1.1558x; 1.1558x over previous
//
#include <hip/hip_runtime.h>
#include <stdint.h>

#define N_NODES 100000
#define N_FEAT 128
#define N_EDGES 3200000

// ---------- bf16 helpers ----------
static __device__ __forceinline__ unsigned int f2bf_u(float f) {
    unsigned int u = __float_as_uint(f);
    u += 0x7FFFu + ((u >> 16) & 1u);   // RNE
    return u >> 16;
}

typedef __bf16 bf16x8 __attribute__((ext_vector_type(8)));
typedef float f32x4 __attribute__((ext_vector_type(4)));

// ---------- Kernel 1 (fused prep) ----------
// blocks [0,12500):      x fp32 -> int8 row-quantized (scale = rowabsmax/127)
// blocks [12500,25000):  CSR row_ptr scatter from sorted edge_dst
// blocks [25000,25064):  filters -> bf16 in MFMA B-fragment-linear order:
//   flat short index i: s=i&7, lane=(i>>3)&63, kkidx=(i>>9)&3, j=i>>11
//   holds F[k][n] with n = j*16 + (lane&15), k = kkidx*32 + (lane>>4)*8 + s
__global__ __launch_bounds__(256) void k_prep(
        const float* __restrict__ x, unsigned int* __restrict__ xi8,
        float* __restrict__ xscale,
        const float* __restrict__ f, unsigned short* __restrict__ fB,
        const int* __restrict__ dst, int* __restrict__ row_ptr) {
    int b = blockIdx.x;
    if (b < 12500) {
        int wave = threadIdx.x >> 6, lane = threadIdx.x & 63;
        int l32 = lane & 31;
        int node = b * 8 + wave * 2 + (lane >> 5);
        float4 v = *(const float4*)(x + (size_t)node * 128 + l32 * 4);
        float am = fmaxf(fmaxf(fabsf(v.x), fabsf(v.y)), fmaxf(fabsf(v.z), fabsf(v.w)));
        for (int d = 1; d < 32; d <<= 1) am = fmaxf(am, __shfl_xor(am, d));
        float s = am * (1.f / 127.f);
        float inv = 127.f / fmaxf(am, 1e-20f);
        int q0 = (int)rintf(v.x * inv), q1 = (int)rintf(v.y * inv);
        int q2 = (int)rintf(v.z * inv), q3 = (int)rintf(v.w * inv);
        xi8[(size_t)node * 32 + l32] = (unsigned int)((q0 & 0xFF) | ((q1 & 0xFF) << 8) |
                                                      ((q2 & 0xFF) << 16) | ((q3 & 0xFF) << 24));
        if (l32 == 0) xscale[node] = s;
    } else if (b < 25000) {
        int e = (b - 12500) * 256 + threadIdx.x;
        if (e >= N_EDGES) return;
        int dcur = dst[e];
        if (e == 0) {
            for (int d = 0; d <= dcur; ++d) row_ptr[d] = 0;
        } else {
            int dprev = dst[e - 1];
            for (int d = dprev + 1; d <= dcur; ++d) row_ptr[d] = e;
        }
        if (e == N_EDGES - 1) {
            for (int d = dcur + 1; d <= N_NODES; ++d) row_ptr[d] = N_EDGES;
        }
    } else {
        int i = (b - 25000) * 256 + threadIdx.x;   // flat fragment-linear index
        if (i >= N_FEAT * N_FEAT) return;
        int n = ((i >> 11) << 4) | ((i >> 3) & 15);
        int k = (((i >> 9) & 3) << 5) | (((i >> 7) & 3) << 3) | (i & 7);
        fB[i] = (unsigned short)f2bf_u(f[k * 128 + n]);
    }
}

// ---------- Kernel 2: per-node weighted aggregation of int8 x (round-5) ----------
__global__ __launch_bounds__(256) void k_aggregate(
        const unsigned int* __restrict__ xi8,    // [N][32] uints (4 int8 each)
        const float* __restrict__ xscale,        // [N]
        const int* __restrict__ src,
        const float* __restrict__ w,
        const int* __restrict__ row_ptr,
        unsigned int* __restrict__ aggb) {       // [N][64] uints (bf16x2)
    __shared__ uint2 smeta[4][64];
    int wave = threadIdx.x >> 6, lane = threadIdx.x & 63;
    int node = blockIdx.x * 4 + wave;
    if (node >= N_NODES) return;
    int half = lane >> 5, f = lane & 31;
    int start = row_ptr[node], end = row_ptr[node + 1];
    float a0 = 0.f, a1 = 0.f, a2 = 0.f, a3 = 0.f;

    for (int e0 = start; e0 < end; e0 += 64) {
        int e = e0 + lane;
        uint2 m = make_uint2(0u, 0u);                    // pad: src=0, w'=0
        if (e < end) {
            int sv = src[e];
            m.x = (unsigned int)sv;
            m.y = __float_as_uint(w[e] * xscale[sv]);    // fold row scale
        }
        smeta[wave][lane] = m;                           // wave-private; no barrier
        int cnt16 = (min(64, end - e0) + 15) & ~15;
        for (int j = 0; j < cnt16; j += 16) {
            unsigned int vv[8]; float wj[8];
#pragma unroll
            for (int u = 0; u < 8; ++u) {
                uint2 mm = smeta[wave][j + u * 2 + half];
                wj[u] = __uint_as_float(mm.y);
                vv[u] = xi8[mm.x * 32 + f];              // 2 edges x 128B / wave
            }
#pragma unroll
            for (int u = 0; u < 8; ++u) {
                int s32 = (int)vv[u];
                a0 = fmaf(wj[u], (float)((s32 << 24) >> 24), a0);
                a1 = fmaf(wj[u], (float)((s32 << 16) >> 24), a1);
                a2 = fmaf(wj[u], (float)((s32 <<  8) >> 24), a2);
                a3 = fmaf(wj[u], (float)( s32        >> 24), a3);
            }
        }
    }
    a0 += __shfl_xor(a0, 32);
    a1 += __shfl_xor(a1, 32);
    a2 += __shfl_xor(a2, 32);
    a3 += __shfl_xor(a3, 32);
    if (half == 0) {
        uint2 o;
        o.x = (f2bf_u(a1) << 16) | f2bf_u(a0);
        o.y = (f2bf_u(a3) << 16) | f2bf_u(a2);
        *(uint2*)(aggb + (size_t)node * 64 + f * 2) = o;
    }
}

// ---------- Kernel 3: out = agg_bf16 @ F ----------
// Block 256 (4 waves), 64 rows/block; B in LDS fragment-linear (32KB exactly,
// 5 blocks/CU); A fragments loaded straight from global (16 rows x 64B
// segments per instr); wave computes 16 rows x 128 cols (8 MFMA col-tiles).
__global__ __launch_bounds__(256) void k_gemm(
        const unsigned short* __restrict__ A,    // [M][128] bf16 (agg)
        const unsigned short* __restrict__ fB,   // fragment-linear B
        float* __restrict__ C) {                 // [M][128] fp32
    __shared__ unsigned short Bbuf[16384];       // 32768 B exactly
    int t = threadIdx.x;
    for (int i = 0; i < 8; ++i)
        ((uint4*)Bbuf)[t + i * 256] = ((const uint4*)fB)[t + i * 256];
    __syncthreads();

    int wave = t >> 6, lane = t & 63, m15 = lane & 15, q = lane >> 4;
    int row = blockIdx.x * 64 + wave * 16 + m15;
    int rowc = min(row, N_NODES - 1);            // clamp loads; stores guarded

    f32x4 acc[8];
#pragma unroll
    for (int j = 0; j < 8; ++j) acc[j] = f32x4{0.f, 0.f, 0.f, 0.f};

#pragma unroll
    for (int kkidx = 0; kkidx < 4; ++kkidx) {
        bf16x8 a = *(const bf16x8*)(A + (size_t)rowc * 128 + kkidx * 32 + q * 8);
#pragma unroll
        for (int j = 0; j < 8; ++j) {
            bf16x8 b = *(const bf16x8*)(Bbuf + (((j * 4 + kkidx) * 64 + lane) * 8));
            acc[j] = __builtin_amdgcn_mfma_f32_16x16x32_bf16(a, b, acc[j], 0, 0, 0);
        }
    }

    int rowbase = blockIdx.x * 64 + wave * 16 + q * 4;   // D: row=q*4+r, col=m15
#pragma unroll
    for (int j = 0; j < 8; ++j)
        for (int r = 0; r < 4; ++r) {
            int gr = rowbase + r;
            if (gr < N_NODES)
                C[(size_t)gr * 128 + j * 16 + m15] = acc[j][r];
        }
}

extern "C" void kernel_launch(void* const* d_in, const int* in_sizes, int n_in,
                              void* d_out, int out_size, void* d_ws, size_t ws_size,
                              hipStream_t stream) {
    const float* x        = (const float*)d_in[0];
    const float* filters  = (const float*)d_in[1];
    const int*   edge_src = (const int*)d_in[2];
    const int*   edge_dst = (const int*)d_in[3];
    const float* edge_w   = (const float*)d_in[4];
    float* out = (float*)d_out;

    char* ws = (char*)d_ws;
    unsigned int*   xi8  = (unsigned int*)  (ws);                          // 12.8 MB
    float*          xsc  = (float*)         (ws + 13ll * 1024 * 1024);     // 400 KB
    unsigned int*   aggb = (unsigned int*)  (ws + 14ll * 1024 * 1024);     // 25.6 MB
    unsigned short* fB   = (unsigned short*)(ws + 40ll * 1024 * 1024);     // 32 KB
    int*            rp   = (int*)           (ws + 41ll * 1024 * 1024);     // 400 KB

    hipLaunchKernelGGL(k_prep, dim3(25064), dim3(256), 0, stream,
                       x, xi8, xsc, filters, fB, edge_dst, rp);
    hipLaunchKernelGGL(k_aggregate, dim3(25000), dim3(256), 0, stream,
                       xi8, xsc, edge_src, edge_w, rp, aggb);
    hipLaunchKernelGGL(k_gemm, dim3(1563), dim3(256), 0, stream,
                       (const unsigned short*)aggb, fB, out);
}